// Round 1
// baseline (366.067 us; speedup 1.0000x reference)
//
#include <hip/hip_runtime.h>
#include <math.h>

// Problem constants (from reference): B=32, S=2048, D=1024, fp32 in/out.
#define BD 32
#define SD 2048
#define DD 1024
#define MASK_PENALTY 100000000.0f
#define RR 8          // rows processed per block iteration
#define NTHREADS 256  // thread t owns d = 4t..4t+3 (float4), 256*4 = D

// Kernel 1: per (batch, S-chunk) partial online-softmax attention.
// Each block produces partial (m, l, o[D]) for its chunk of rows.
__global__ __launch_bounds__(NTHREADS) void attn_partial(
    const float* __restrict__ target,   // [B,D]
    const float* __restrict__ context,  // [B,S,D]
    const float* __restrict__ mask,     // [B,S]
    float* __restrict__ wsO,            // [B*C, D]
    float* __restrict__ wsM,            // [B*C]
    float* __restrict__ wsL,            // [B*C]
    int C)                              // chunks per batch
{
    const int g = blockIdx.x;           // 0..B*C-1
    const int b = g / C;
    const int c = g % C;
    const int rows = SD / C;
    const int s0 = c * rows;
    const int t = threadIdx.x;
    const int lane = t & 63;
    const int wave = t >> 6;

    __shared__ float s_part[2][4][RR];  // per-wave partial dots
    __shared__ float s_sc[2][RR];       // final scores for the row-group

    const float4 tgt = *(const float4*)(target + (size_t)b * DD + t * 4);
    const float* ctx = context + ((size_t)b * SD + s0) * DD + t * 4;
    const float* mk  = mask + (size_t)b * SD + s0;

    float4 o = make_float4(0.f, 0.f, 0.f, 0.f);
    float m = -INFINITY;
    float l = 0.f;

    for (int i = 0; i < rows; i += RR) {
        const int buf = (i / RR) & 1;
        float4 x[RR];
        float part[RR];
        // coalesced float4 loads: one read of context, kept in registers for
        // both the dot product AND the weighted accumulation (no re-read)
        #pragma unroll
        for (int r = 0; r < RR; ++r)
            x[r] = *(const float4*)(ctx + (size_t)(i + r) * DD);
        #pragma unroll
        for (int r = 0; r < RR; ++r)
            part[r] = x[r].x * tgt.x + x[r].y * tgt.y + x[r].z * tgt.z + x[r].w * tgt.w;
        // wave-level reduce (64 lanes), independent chains for ILP
        #pragma unroll
        for (int r = 0; r < RR; ++r) {
            #pragma unroll
            for (int off = 32; off > 0; off >>= 1)
                part[r] += __shfl_xor(part[r], off);
        }
        if (lane == 0) {
            #pragma unroll
            for (int r = 0; r < RR; ++r) s_part[buf][wave][r] = part[r];
        }
        __syncthreads();
        if (t < RR) {
            float sc = s_part[buf][0][t] + s_part[buf][1][t] +
                       s_part[buf][2][t] + s_part[buf][3][t];
            sc += (mk[i + t] - 1.0f) * MASK_PENALTY;
            s_sc[buf][t] = sc;
        }
        __syncthreads();
        // online-softmax update of (m, l, o)
        float sc[RR];
        float mnew = m;
        #pragma unroll
        for (int r = 0; r < RR; ++r) { sc[r] = s_sc[buf][r]; mnew = fmaxf(mnew, sc[r]); }
        const float alpha = __expf(m - mnew);   // m=-inf first iter -> alpha=0
        float p[RR];
        float psum = 0.f;
        #pragma unroll
        for (int r = 0; r < RR; ++r) { p[r] = __expf(sc[r] - mnew); psum += p[r]; }
        l = l * alpha + psum;
        o.x *= alpha; o.y *= alpha; o.z *= alpha; o.w *= alpha;
        #pragma unroll
        for (int r = 0; r < RR; ++r) {
            o.x += p[r] * x[r].x; o.y += p[r] * x[r].y;
            o.z += p[r] * x[r].z; o.w += p[r] * x[r].w;
        }
        m = mnew;
    }

    *(float4*)(wsO + (size_t)g * DD + t * 4) = o;
    if (t == 0) { wsM[g] = m; wsL[g] = l; }
}

// Kernel 2: combine C partials per batch with global max rescaling.
__global__ __launch_bounds__(NTHREADS) void attn_combine(
    const float* __restrict__ wsO,
    const float* __restrict__ wsM,
    const float* __restrict__ wsL,
    float* __restrict__ out,
    int C)
{
    const int b = blockIdx.x;
    const int t = threadIdx.x;
    __shared__ float w[64];  // per-chunk normalized weights (C <= 64)

    if (t < 64) {
        float mv = (t < C) ? wsM[b * C + t] : -INFINITY;
        float mred = mv;
        #pragma unroll
        for (int off = 32; off > 0; off >>= 1)
            mred = fmaxf(mred, __shfl_xor(mred, off));
        float lw = (t < C) ? wsL[b * C + t] * __expf(mv - mred) : 0.f;
        float lsum = lw;
        #pragma unroll
        for (int off = 32; off > 0; off >>= 1)
            lsum += __shfl_xor(lsum, off);
        w[t] = (t < C) ? __expf(mv - mred) / lsum : 0.f;
    }
    __syncthreads();

    float4 acc = make_float4(0.f, 0.f, 0.f, 0.f);
    for (int c = 0; c < C; ++c) {
        float4 v = *(const float4*)(wsO + ((size_t)(b * C + c)) * DD + t * 4);
        float wc = w[c];
        acc.x += wc * v.x; acc.y += wc * v.y; acc.z += wc * v.z; acc.w += wc * v.w;
    }
    *(float4*)(out + (size_t)b * DD + t * 4) = acc;
}

extern "C" void kernel_launch(void* const* d_in, const int* in_sizes, int n_in,
                              void* d_out, int out_size, void* d_ws, size_t ws_size,
                              hipStream_t stream) {
    const float* target  = (const float*)d_in[0];  // [B,D]
    const float* context = (const float*)d_in[1];  // [B,S,D]
    const float* mask    = (const float*)d_in[2];  // [B,S]
    float* out = (float*)d_out;                    // [B,D]

    // chunks per batch: 32 -> 1024 blocks (4/CU). Fall back if ws too small.
    int C = 32;
    while (C > 1 && (size_t)BD * C * (DD + 2) * sizeof(float) > ws_size) C >>= 1;

    float* wsO = (float*)d_ws;                 // [B*C, D]
    float* wsM = wsO + (size_t)BD * C * DD;    // [B*C]
    float* wsL = wsM + (size_t)BD * C;         // [B*C]

    attn_partial<<<BD * C, NTHREADS, 0, stream>>>(target, context, mask, wsO, wsM, wsL, C);
    attn_combine<<<BD, NTHREADS, 0, stream>>>(wsO, wsM, wsL, out, C);
}